// Round 6
// baseline (1112.751 us; speedup 1.0000x reference)
//
#include <hip/hip_runtime.h>

#define N_NODESC 50000
#define N_EDGESC 1600000
#define FEAT 128
#define NREL 8
#define NSEG (N_NODESC * NREL)
#define NGRAPH 64
#define NKC 36             // K-total 1152 = 36 chunks of 32
#define WPACK_ELEMS (NKC * 4 * 128 * 8)  // 147456
#define MTILE 128

typedef float f32x4 __attribute__((ext_vector_type(4)));
typedef short bf16x8 __attribute__((ext_vector_type(8)));

static inline size_t align256(size_t x) { return (x + 255) & ~(size_t)255; }

__device__ __forceinline__ unsigned short f2bf(float f) {
  unsigned int u = __float_as_uint(f);
  unsigned int r = (u + 0x7fffu + ((u >> 16) & 1u)) >> 16;  // RNE
  return (unsigned short)r;
}
__device__ __forceinline__ float bf2f(unsigned short h) {
  return __uint_as_float(((unsigned int)h) << 16);
}

// ---------------- utility: zero ints ----------------
__global__ void k_zero(int* __restrict__ p, int n) {
  int i = blockIdx.x * blockDim.x + threadIdx.x;
  int stride = gridDim.x * blockDim.x;
  for (; i < n; i += stride) p[i] = 0;
}

// ---------------- edge type + segment + histogram ----------------
__global__ void k_edge_hist(const int* __restrict__ ei, const float* __restrict__ eattr,
                            int* __restrict__ seg, int* __restrict__ cnt) {
  int e = blockIdx.x * blockDim.x + threadIdx.x;
  if (e >= N_EDGESC) return;
  int dst = ei[N_EDGESC + e];
  const float4* ap = (const float4*)(eattr + (size_t)e * 8);
  float4 a0 = ap[0], a1 = ap[1];
  int ty = 0;
  if (a0.y > 0.5f) ty = 1;
  if (a0.z > 0.5f) ty = 2;
  if (a0.w > 0.5f) ty = 3;
  if (a1.x > 0.5f) ty = 4;
  if (a1.y > 0.5f) ty = 5;
  if (a1.z > 0.5f) ty = 6;
  if (a1.w > 0.5f) ty = 7;
  int s = dst * NREL + ty;
  seg[e] = s;
  atomicAdd(&cnt[s], 1);
}

// ---------------- scan over NSEG counts ----------------
__global__ void k_scan1(const int* __restrict__ cnt, int* __restrict__ outIncl,
                        int* __restrict__ bsums, int n) {
  __shared__ int sd[256];
  int t = threadIdx.x;
  int base = blockIdx.x * 4096 + t * 16;
  int v[16];
  int s = 0;
#pragma unroll
  for (int j = 0; j < 16; ++j) {
    int idx = base + j;
    int x = (idx < n) ? cnt[idx] : 0;
    s += x;
    v[j] = s;
  }
  sd[t] = s;
  __syncthreads();
  for (int off = 1; off < 256; off <<= 1) {
    int add = (t >= off) ? sd[t - off] : 0;
    __syncthreads();
    sd[t] += add;
    __syncthreads();
  }
  int prev = (t > 0) ? sd[t - 1] : 0;
#pragma unroll
  for (int j = 0; j < 16; ++j) {
    int idx = base + j;
    if (idx < n) outIncl[idx] = prev + v[j];
  }
  if (t == 255) bsums[blockIdx.x] = sd[255];
}

__global__ void k_scan2(int* __restrict__ bsums, int nb) {
  __shared__ int sd[128];
  int t = threadIdx.x;
  int v = (t < nb) ? bsums[t] : 0;
  sd[t] = v;
  __syncthreads();
  for (int off = 1; off < 128; off <<= 1) {
    int add = (t >= off) ? sd[t - off] : 0;
    __syncthreads();
    sd[t] += add;
    __syncthreads();
  }
  if (t < nb) bsums[t] = sd[t] - v;  // exclusive
}

__global__ void k_scan3(int* __restrict__ offsets, const int* __restrict__ bsums, int n) {
  int i = blockIdx.x * blockDim.x + threadIdx.x;
  if (i == 0) offsets[0] = 0;
  if (i < n) offsets[i + 1] += bsums[i >> 12];
}

// ---------------- scatter into CSR ----------------
__global__ void k_scatter(const int* __restrict__ ei, const int* __restrict__ seg,
                          const int* __restrict__ offsets, int* __restrict__ cursor,
                          int* __restrict__ ssrc) {
  int e = blockIdx.x * blockDim.x + threadIdx.x;
  if (e >= N_EDGESC) return;
  int s = seg[e];
  int p = offsets[s] + atomicAdd(&cursor[s], 1);
  ssrc[p] = ei[e];
}

// ---------------- weight pack: W[8][128][128] + root[128][128] -> bf16 hi/lo ----------------
// fragment-major layout: idx = ((slot*128)+n)*8 + j, slot = kc*4+g, k = kc*32+g*8+j
__global__ void k_wpack(const float* __restrict__ W, const float* __restrict__ root,
                        unsigned short* __restrict__ whi, unsigned short* __restrict__ wlo) {
  int idx = blockIdx.x * 256 + threadIdx.x;
  if (idx >= WPACK_ELEMS) return;
  int j = idx & 7;
  int n = (idx >> 3) & 127;
  int slot = idx >> 10;
  int k = slot * 8 + j;
  float v = (k < 1024) ? W[(size_t)k * 128 + n] : root[(size_t)(k - 1024) * 128 + n];
  unsigned short hi = f2bf(v);
  float lof = v - bf2f(hi);
  whi[idx] = hi;
  wlo[idx] = f2bf(lof);
}

// ---------------- fused RGCN layer: per-slab aggregate (regs) -> LDS bf16 -> MFMA ----------------
// 512 threads = 8 waves; tile = 128 nodes x 128 out-cols; wave owns 16 rows.
// slab r<8: mean-aggregate rel r (group of 32 lanes walks one segment uniformly);
// slab 8: root term (direct x rows). K per slab = 128 = 4 MFMA chunks of 32.
__global__ __launch_bounds__(512, 4) void k_layer_fused(
    const float* __restrict__ in,
    const unsigned short* __restrict__ Whi, const unsigned short* __restrict__ Wlo,
    const float* __restrict__ bias,
    const int* __restrict__ offsets, const int* __restrict__ ssrc,
    float* __restrict__ out) {
  __shared__ unsigned short Ahi[16 * 128 * 8] __attribute__((aligned(16)));  // [G=kslab/8][row][j]
  __shared__ unsigned short Alo[16 * 128 * 8] __attribute__((aligned(16)));
  __shared__ unsigned short Bhi[4 * 128 * 8] __attribute__((aligned(16)));   // [g][n][j]
  __shared__ unsigned short Blo[4 * 128 * 8] __attribute__((aligned(16)));

  const int t = threadIdx.x;
  const int lane = t & 63, wave = t >> 6;  // 8 waves
  const int l15 = lane & 15, lg = lane >> 4;
  const int wrow0 = wave * 16;             // wave's 16 output rows
  const int grp = t >> 5, l32 = t & 31;    // 16 agg groups of 32 lanes
  const int m0 = blockIdx.x * MTILE;

  f32x4 acc[8];
#pragma unroll
  for (int b = 0; b < 8; ++b) acc[b] = (f32x4){0.f, 0.f, 0.f, 0.f};

  for (int slab = 0; slab < 9; ++slab) {
    // ---- phase 1: aggregate slab into registers (8 nodes per group) ----
    float4 sreg[8];
#pragma unroll
    for (int nn = 0; nn < 8; ++nn) {
      int m = grp * 8 + nn;
      int n = m0 + m;
      float4 s = make_float4(0.f, 0.f, 0.f, 0.f);
      if (n < N_NODESC) {
        if (slab < 8) {
          int sidx = n * NREL + slab;
          int beg = offsets[sidx], end = offsets[sidx + 1];
          for (int e = beg; e < end; ++e) {
            int sp = ssrc[e];
            const float4 v = *(const float4*)&in[(size_t)sp * FEAT + l32 * 4];
            s.x += v.x; s.y += v.y; s.z += v.z; s.w += v.w;
          }
          int c = end - beg;
          if (c > 1) {
            float inv = 1.0f / (float)c;
            s.x *= inv; s.y *= inv; s.z *= inv; s.w *= inv;
          }
        } else {
          s = *(const float4*)&in[(size_t)n * FEAT + l32 * 4];
        }
      }
      sreg[nn] = s;
    }

    __syncthreads();  // previous slab's A-LDS reads complete

    // ---- phase 2: convert + store A slab to LDS (hi/lo, fragment layout) ----
    {
      const int G = l32 >> 1;              // kslab = l32*4+i -> G = kslab>>3
      const int j0 = (l32 & 1) * 4;
#pragma unroll
      for (int nn = 0; nn < 8; ++nn) {
        int m = grp * 8 + nn;
        union { unsigned short u[4]; uint2 v; } ph, pl;
        const float* sf = (const float*)&sreg[nn];
#pragma unroll
        for (int i = 0; i < 4; ++i) {
          unsigned short hi = f2bf(sf[i]);
          ph.u[i] = hi;
          pl.u[i] = f2bf(sf[i] - bf2f(hi));
        }
        *(uint2*)&Ahi[((size_t)(G * 128 + m)) * 8 + j0] = ph.v;
        *(uint2*)&Alo[((size_t)(G * 128 + m)) * 8 + j0] = pl.v;
      }
    }

    // ---- phase 3: 4 MFMA chunks of K=32 ----
    for (int kc4 = 0; kc4 < 4; ++kc4) {
      const int kcg = slab * 4 + kc4;
      uint4 bh = ((const uint4*)(Whi + (size_t)kcg * 4096))[t];
      uint4 blv = ((const uint4*)(Wlo + (size_t)kcg * 4096))[t];
      __syncthreads();  // kc4=0: A stores ordered before reads; else: prev B reads done
      ((uint4*)Bhi)[t] = bh;
      ((uint4*)Blo)[t] = blv;
      __syncthreads();

      int ar = wrow0 + l15;
      bf16x8 ah = *(const bf16x8*)&Ahi[((size_t)((kc4 * 4 + lg) * 128 + ar)) * 8];
      bf16x8 al = *(const bf16x8*)&Alo[((size_t)((kc4 * 4 + lg) * 128 + ar)) * 8];
#pragma unroll
      for (int nf = 0; nf < 8; ++nf) {
        int bn = nf * 16 + l15;
        bf16x8 b1 = *(const bf16x8*)&Bhi[((size_t)(lg * 128 + bn)) * 8];
        bf16x8 b2 = *(const bf16x8*)&Blo[((size_t)(lg * 128 + bn)) * 8];
        acc[nf] = __builtin_amdgcn_mfma_f32_16x16x32_bf16(ah, b1, acc[nf], 0, 0, 0);
        acc[nf] = __builtin_amdgcn_mfma_f32_16x16x32_bf16(ah, b2, acc[nf], 0, 0, 0);
        acc[nf] = __builtin_amdgcn_mfma_f32_16x16x32_bf16(al, b1, acc[nf], 0, 0, 0);
      }
    }
  }

  // ---- epilogue: bias + relu + store ----
  float bcol[8];
#pragma unroll
  for (int nf = 0; nf < 8; ++nf) bcol[nf] = bias[nf * 16 + l15];
#pragma unroll
  for (int nf = 0; nf < 8; ++nf)
#pragma unroll
    for (int j = 0; j < 4; ++j) {
      int grow = m0 + wrow0 + lg * 4 + j;
      if (grow < N_NODESC) {
        float v = acc[nf][j] + bcol[nf];
        v = v > 0.f ? v : 0.f;
        out[(size_t)grow * FEAT + nf * 16 + l15] = v;
      }
    }
}

// ---------------- global mean pool + final linear ----------------
__global__ void k_pool(const float* __restrict__ h, const int* __restrict__ batch,
                       const float* __restrict__ lw, const float* __restrict__ lb,
                       float* __restrict__ out) {
  __shared__ float sums[8][128];
  __shared__ float prow[128];
  int gidx = blockIdx.x, t = threadIdx.x;
  int f = t & 127, grp = t >> 7;
  int lo = 0, hi = N_NODESC;
  while (lo < hi) {
    int mid = (lo + hi) >> 1;
    if (batch[mid] < gidx) lo = mid + 1; else hi = mid;
  }
  int start = lo;
  hi = N_NODESC;
  while (lo < hi) {
    int mid = (lo + hi) >> 1;
    if (batch[mid] < gidx + 1) lo = mid + 1; else hi = mid;
  }
  int end = lo;
  float s = 0.f;
  for (int n = start + grp; n < end; n += 8) s += h[(size_t)n * FEAT + f];
  sums[grp][f] = s;
  __syncthreads();
  if (grp == 0) {
    float tot = 0.f;
#pragma unroll
    for (int gg = 0; gg < 8; ++gg) tot += sums[gg][f];
    int c = end - start;
    prow[f] = (c > 0) ? tot / (float)c : 0.f;
  }
  __syncthreads();
  float a = 0.f;
  for (int k = grp * 16; k < grp * 16 + 16; ++k) a = fmaf(prow[k], lw[(size_t)k * FEAT + f], a);
  __syncthreads();
  sums[grp][f] = a;
  __syncthreads();
  if (grp == 0) {
    float tot = lb[f];
#pragma unroll
    for (int gg = 0; gg < 8; ++gg) tot += sums[gg][f];
    out[(size_t)gidx * FEAT + f] = tot;
  }
}

extern "C" void kernel_launch(void* const* d_in, const int* in_sizes, int n_in,
                              void* d_out, int out_size, void* d_ws, size_t ws_size,
                              hipStream_t stream) {
  const float* x = (const float*)d_in[0];
  const int* ei = (const int*)d_in[1];
  const float* eattr = (const float*)d_in[2];
  const int* batch = (const int*)d_in[3];
  const float* Wl[3] = {(const float*)d_in[4], (const float*)d_in[7], (const float*)d_in[10]};
  const float* rl[3] = {(const float*)d_in[5], (const float*)d_in[8], (const float*)d_in[11]};
  const float* bl[3] = {(const float*)d_in[6], (const float*)d_in[9], (const float*)d_in[12]};
  const float* lw = (const float*)d_in[13];
  const float* lb = (const float*)d_in[14];
  float* out = (float*)d_out;
  (void)n_in; (void)in_sizes; (void)out_size; (void)ws_size;

  // ---- workspace carve (~70 MB) ----
  size_t pos = 0;
  char* base = (char*)d_ws;
  auto alloc = [&](size_t bytes) { char* q = base + pos; pos += align256(bytes); return q; };
  int* seg = (int*)alloc(sizeof(int) * (size_t)N_EDGESC);
  int* cntcur = (int*)alloc(sizeof(int) * (size_t)2 * NSEG);
  int* cnt = cntcur;
  int* cursor = cntcur + NSEG;
  int* offsets = (int*)alloc(sizeof(int) * (size_t)(NSEG + 1));
  int* bsums = (int*)alloc(sizeof(int) * 1024);
  int* ssrc = (int*)alloc(sizeof(int) * (size_t)N_EDGESC);
  float* h1 = (float*)alloc(sizeof(float) * (size_t)N_NODESC * FEAT);
  float* h2 = (float*)alloc(sizeof(float) * (size_t)N_NODESC * FEAT);
  unsigned short* whi = (unsigned short*)alloc(sizeof(unsigned short) * (size_t)WPACK_ELEMS);
  unsigned short* wlo = (unsigned short*)alloc(sizeof(unsigned short) * (size_t)WPACK_ELEMS);

  // ---- build CSR (counting sort by seg = dst*8 + rel) ----
  hipLaunchKernelGGL(k_zero, dim3(2048), dim3(256), 0, stream, cntcur, 2 * NSEG);
  hipLaunchKernelGGL(k_edge_hist, dim3((N_EDGESC + 255) / 256), dim3(256), 0, stream,
                     ei, eattr, seg, cnt);
  int nbScan = (NSEG + 4095) / 4096;  // 98
  hipLaunchKernelGGL(k_scan1, dim3(nbScan), dim3(256), 0, stream, cnt, offsets + 1, bsums, NSEG);
  hipLaunchKernelGGL(k_scan2, dim3(1), dim3(128), 0, stream, bsums, nbScan);
  hipLaunchKernelGGL(k_scan3, dim3((NSEG + 255) / 256), dim3(256), 0, stream, offsets, bsums, NSEG);
  hipLaunchKernelGGL(k_scatter, dim3((N_EDGESC + 255) / 256), dim3(256), 0, stream,
                     ei, seg, offsets, cursor, ssrc);

  // ---- 3 fused RGCN layers ----
  int nblk = (N_NODESC + MTILE - 1) / MTILE;  // 391
  const float* inPtr = x;
  float* outPtr = h1;
  for (int L = 0; L < 3; ++L) {
    hipLaunchKernelGGL(k_wpack, dim3((WPACK_ELEMS + 255) / 256), dim3(256), 0, stream,
                       Wl[L], rl[L], whi, wlo);
    hipLaunchKernelGGL(k_layer_fused, dim3(nblk), dim3(512), 0, stream,
                       inPtr, whi, wlo, bl[L], offsets, ssrc, outPtr);
    inPtr = outPtr;
    outPtr = (L == 0) ? h2 : h1;
  }

  // ---- pool + final linear ----
  hipLaunchKernelGGL(k_pool, dim3(NGRAPH), dim3(1024), 0, stream, h1, batch, lw, lb, out);
}

// Round 7
// 971.201 us; speedup vs baseline: 1.1457x; 1.1457x over previous
//
#include <hip/hip_runtime.h>

#define N_NODESC 50000
#define N_EDGESC 1600000
#define FEAT 128
#define NREL 8
#define NSEG (N_NODESC * NREL)
#define NGRAPH 64
#define KTOT 1152          // 8*128 agg + 128 root
#define NKC 36             // KTOT/32
#define WPACK_ELEMS (NKC * 4 * 128 * 8)  // 147456

typedef float f32x4 __attribute__((ext_vector_type(4)));
typedef short bf16x8 __attribute__((ext_vector_type(8)));

static inline size_t align256(size_t x) { return (x + 255) & ~(size_t)255; }

__device__ __forceinline__ unsigned short f2bf(float f) {
  unsigned int u = __float_as_uint(f);
  unsigned int r = (u + 0x7fffu + ((u >> 16) & 1u)) >> 16;  // RNE
  return (unsigned short)r;
}
__device__ __forceinline__ float bf2f(unsigned short h) {
  return __uint_as_float(((unsigned int)h) << 16);
}

// ---------------- utility: zero ints ----------------
__global__ void k_zero(int* __restrict__ p, int n) {
  int i = blockIdx.x * blockDim.x + threadIdx.x;
  int stride = gridDim.x * blockDim.x;
  for (; i < n; i += stride) p[i] = 0;
}

// ---------------- edge type + segment + histogram ----------------
__global__ void k_edge_hist(const int* __restrict__ ei, const float* __restrict__ eattr,
                            int* __restrict__ seg, int* __restrict__ cnt) {
  int e = blockIdx.x * blockDim.x + threadIdx.x;
  if (e >= N_EDGESC) return;
  int dst = ei[N_EDGESC + e];
  const float4* ap = (const float4*)(eattr + (size_t)e * 8);
  float4 a0 = ap[0], a1 = ap[1];
  int ty = 0;
  if (a0.y > 0.5f) ty = 1;
  if (a0.z > 0.5f) ty = 2;
  if (a0.w > 0.5f) ty = 3;
  if (a1.x > 0.5f) ty = 4;
  if (a1.y > 0.5f) ty = 5;
  if (a1.z > 0.5f) ty = 6;
  if (a1.w > 0.5f) ty = 7;
  int s = dst * NREL + ty;
  seg[e] = s;
  atomicAdd(&cnt[s], 1);
}

// ---------------- scan over NSEG counts ----------------
__global__ void k_scan1(const int* __restrict__ cnt, int* __restrict__ outIncl,
                        int* __restrict__ bsums, int n) {
  __shared__ int sd[256];
  int t = threadIdx.x;
  int base = blockIdx.x * 4096 + t * 16;
  int v[16];
  int s = 0;
#pragma unroll
  for (int j = 0; j < 16; ++j) {
    int idx = base + j;
    int x = (idx < n) ? cnt[idx] : 0;
    s += x;
    v[j] = s;
  }
  sd[t] = s;
  __syncthreads();
  for (int off = 1; off < 256; off <<= 1) {
    int add = (t >= off) ? sd[t - off] : 0;
    __syncthreads();
    sd[t] += add;
    __syncthreads();
  }
  int prev = (t > 0) ? sd[t - 1] : 0;
#pragma unroll
  for (int j = 0; j < 16; ++j) {
    int idx = base + j;
    if (idx < n) outIncl[idx] = prev + v[j];
  }
  if (t == 255) bsums[blockIdx.x] = sd[255];
}

__global__ void k_scan2(int* __restrict__ bsums, int nb) {
  __shared__ int sd[128];
  int t = threadIdx.x;
  int v = (t < nb) ? bsums[t] : 0;
  sd[t] = v;
  __syncthreads();
  for (int off = 1; off < 128; off <<= 1) {
    int add = (t >= off) ? sd[t - off] : 0;
    __syncthreads();
    sd[t] += add;
    __syncthreads();
  }
  if (t < nb) bsums[t] = sd[t] - v;  // exclusive
}

__global__ void k_scan3(int* __restrict__ offsets, const int* __restrict__ bsums, int n) {
  int i = blockIdx.x * blockDim.x + threadIdx.x;
  if (i == 0) offsets[0] = 0;
  if (i < n) offsets[i + 1] += bsums[i >> 12];
}

// ---------------- scatter into CSR ----------------
__global__ void k_scatter(const int* __restrict__ ei, const int* __restrict__ seg,
                          const int* __restrict__ offsets, int* __restrict__ cursor,
                          int* __restrict__ ssrc) {
  int e = blockIdx.x * blockDim.x + threadIdx.x;
  if (e >= N_EDGESC) return;
  int s = seg[e];
  int p = offsets[s] + atomicAdd(&cursor[s], 1);
  ssrc[p] = ei[e];
}

// ---------------- segment-parallel mean aggregation, 4-deep MLP ----------------
// one 32-lane group per segment; lane l handles features [4l, 4l+4)
__global__ __launch_bounds__(256, 8) void k_agg(
    const float* __restrict__ in, const int* __restrict__ offsets,
    const int* __restrict__ ssrc, float* __restrict__ agg,
    int segBase, int segCount) {
  int t = blockIdx.x * blockDim.x + threadIdx.x;
  int ul = t >> 5;
  int l = t & 31;
  if (ul >= segCount) return;
  int u = segBase + ul;
  int beg = offsets[u], end = offsets[u + 1];
  float4 s = make_float4(0.f, 0.f, 0.f, 0.f);
  // 4-wide predicated unroll: 4 independent ssrc loads + 4 independent gathers
  for (int base = beg; base < end; base += 4) {
    int last = end - 1;
    int e1 = base + 1 <= last ? base + 1 : last;
    int e2 = base + 2 <= last ? base + 2 : last;
    int e3 = base + 3 <= last ? base + 3 : last;
    int i0 = ssrc[base], i1 = ssrc[e1], i2 = ssrc[e2], i3 = ssrc[e3];
    float4 v0 = *(const float4*)&in[(size_t)i0 * FEAT + l * 4];
    float4 v1 = *(const float4*)&in[(size_t)i1 * FEAT + l * 4];
    float4 v2 = *(const float4*)&in[(size_t)i2 * FEAT + l * 4];
    float4 v3 = *(const float4*)&in[(size_t)i3 * FEAT + l * 4];
    s.x += v0.x; s.y += v0.y; s.z += v0.z; s.w += v0.w;
    if (base + 1 < end) { s.x += v1.x; s.y += v1.y; s.z += v1.z; s.w += v1.w; }
    if (base + 2 < end) { s.x += v2.x; s.y += v2.y; s.z += v2.z; s.w += v2.w; }
    if (base + 3 < end) { s.x += v3.x; s.y += v3.y; s.z += v3.z; s.w += v3.w; }
  }
  int c = end - beg;
  if (c > 1) {
    float inv = 1.0f / (float)c;
    s.x *= inv; s.y *= inv; s.z *= inv; s.w *= inv;
  }
  *(float4*)&agg[(size_t)ul * FEAT + l * 4] = s;
}

// ---------------- weight pack: W[8][128][128] + root[128][128] -> bf16 hi/lo ----------------
// fragment-major layout: idx = ((slot*128)+n)*8 + j, slot = kc*4+g, k = kc*32+g*8+j
__global__ void k_wpack(const float* __restrict__ W, const float* __restrict__ root,
                        unsigned short* __restrict__ whi, unsigned short* __restrict__ wlo) {
  int idx = blockIdx.x * 256 + threadIdx.x;
  if (idx >= WPACK_ELEMS) return;
  int j = idx & 7;
  int n = (idx >> 3) & 127;
  int slot = idx >> 10;
  int k = slot * 8 + j;
  float v = (k < 1024) ? W[(size_t)k * 128 + n] : root[(size_t)(k - 1024) * 128 + n];
  unsigned short hi = f2bf(v);
  float lof = v - bf2f(hi);
  whi[idx] = hi;
  wlo[idx] = f2bf(lof);
}

// ---------------- MFMA GEMM: out = relu(A @ Wfull + bias), A = [agg | x], K=1152 ----------------
// block: 128 rows x 128 cols, 256 threads (4 waves), wave = 32 rows x 128 cols
__global__ __launch_bounds__(256, 2) void k_gemm_mfma(
    const float* __restrict__ aggc,  // [rows][1024] chunk-local
    const float* __restrict__ xin,   // [N][128]
    const unsigned short* __restrict__ Whi, const unsigned short* __restrict__ Wlo,
    const float* __restrict__ bias, float* __restrict__ out,
    int n0g, int rows) {
  __shared__ unsigned short Ahi[4 * 128 * 8] __attribute__((aligned(16)));  // [g][row][j]
  __shared__ unsigned short Alo[4 * 128 * 8] __attribute__((aligned(16)));
  __shared__ unsigned short Bhi[4 * 128 * 8] __attribute__((aligned(16)));  // [g][n][j]
  __shared__ unsigned short Blo[4 * 128 * 8] __attribute__((aligned(16)));

  const int t = threadIdx.x;
  const int lane = t & 63, wave = t >> 6;
  const int l15 = lane & 15, lg = lane >> 4;
  const int wrow0 = wave * 32;
  const int m0 = blockIdx.x * 128;
  const int srow = t >> 1, half = t & 1;

  f32x4 acc[2][8];
#pragma unroll
  for (int a = 0; a < 2; ++a)
#pragma unroll
    for (int b = 0; b < 8; ++b) acc[a][b] = (f32x4){0.f, 0.f, 0.f, 0.f};

  for (int kc = 0; kc < NKC; ++kc) {
    // ---- load A slab (fp32) ----
    int rowc = srow;
    if (m0 + rowc >= rows) rowc = rows - 1 - m0;  // clamp (garbage rows masked later)
    if (rowc < 0) rowc = 0;
    const float* asrc = (kc < 32)
        ? (aggc + (size_t)(m0 + rowc) * 1024 + kc * 32 + half * 16)
        : (xin + (size_t)(n0g + m0 + rowc) * FEAT + (kc - 32) * 32 + half * 16);
    float4 av[4];
#pragma unroll
    for (int q = 0; q < 4; ++q) av[q] = ((const float4*)asrc)[q];
    // ---- load B slab (already packed bf16 hi/lo, contiguous 8KB each) ----
    const uint4* bhs = (const uint4*)(Whi + (size_t)kc * 4096);
    const uint4* bls = (const uint4*)(Wlo + (size_t)kc * 4096);
    uint4 bh0 = bhs[t * 2], bh1 = bhs[t * 2 + 1];
    uint4 bl0 = bls[t * 2], bl1 = bls[t * 2 + 1];

    __syncthreads();  // previous iteration's LDS reads complete

    // ---- convert + pack A into LDS ----
    const float* avf = (const float*)av;
#pragma unroll
    for (int gg = 0; gg < 2; ++gg) {
      union { unsigned short u[8]; uint4 v; } ph, pl;
#pragma unroll
      for (int j = 0; j < 8; ++j) {
        float f = avf[gg * 8 + j];
        unsigned short hi = f2bf(f);
        ph.u[j] = hi;
        pl.u[j] = f2bf(f - bf2f(hi));
      }
      int g = half * 2 + gg;
      *(uint4*)&Ahi[((size_t)(g * 128 + srow)) * 8] = ph.v;
      *(uint4*)&Alo[((size_t)(g * 128 + srow)) * 8] = pl.v;
    }
    // ---- store B into LDS (straight copy) ----
    ((uint4*)Bhi)[t * 2] = bh0;
    ((uint4*)Bhi)[t * 2 + 1] = bh1;
    ((uint4*)Blo)[t * 2] = bl0;
    ((uint4*)Blo)[t * 2 + 1] = bl1;

    __syncthreads();

    // ---- fragments + MFMA ----
    bf16x8 ah[2], al[2];
#pragma unroll
    for (int mf = 0; mf < 2; ++mf) {
      int ar = wrow0 + mf * 16 + l15;
      ah[mf] = *(const bf16x8*)&Ahi[((size_t)(lg * 128 + ar)) * 8];
      al[mf] = *(const bf16x8*)&Alo[((size_t)(lg * 128 + ar)) * 8];
    }
#pragma unroll
    for (int nf = 0; nf < 8; ++nf) {
      int bn = nf * 16 + l15;
      bf16x8 bh = *(const bf16x8*)&Bhi[((size_t)(lg * 128 + bn)) * 8];
      bf16x8 bl = *(const bf16x8*)&Blo[((size_t)(lg * 128 + bn)) * 8];
#pragma unroll
      for (int mf = 0; mf < 2; ++mf) {
        acc[mf][nf] = __builtin_amdgcn_mfma_f32_16x16x32_bf16(ah[mf], bh, acc[mf][nf], 0, 0, 0);
        acc[mf][nf] = __builtin_amdgcn_mfma_f32_16x16x32_bf16(ah[mf], bl, acc[mf][nf], 0, 0, 0);
        acc[mf][nf] = __builtin_amdgcn_mfma_f32_16x16x32_bf16(al[mf], bh, acc[mf][nf], 0, 0, 0);
      }
    }
  }

  // ---- epilogue: bias + relu + store ----
  float bcol[8];
#pragma unroll
  for (int nf = 0; nf < 8; ++nf) bcol[nf] = bias[nf * 16 + l15];
#pragma unroll
  for (int mf = 0; mf < 2; ++mf)
#pragma unroll
    for (int nf = 0; nf < 8; ++nf)
#pragma unroll
      for (int j = 0; j < 4; ++j) {
        int grow = m0 + wrow0 + mf * 16 + lg * 4 + j;
        if (grow < rows) {
          float v = acc[mf][nf][j] + bcol[nf];
          v = v > 0.f ? v : 0.f;
          out[(size_t)(n0g + grow) * FEAT + nf * 16 + l15] = v;
        }
      }
}

// ---------------- global mean pool + final linear ----------------
__global__ void k_pool(const float* __restrict__ h, const int* __restrict__ batch,
                       const float* __restrict__ lw, const float* __restrict__ lb,
                       float* __restrict__ out) {
  __shared__ float sums[8][128];
  __shared__ float prow[128];
  int gidx = blockIdx.x, t = threadIdx.x;
  int f = t & 127, grp = t >> 7;
  int lo = 0, hi = N_NODESC;
  while (lo < hi) {
    int mid = (lo + hi) >> 1;
    if (batch[mid] < gidx) lo = mid + 1; else hi = mid;
  }
  int start = lo;
  hi = N_NODESC;
  while (lo < hi) {
    int mid = (lo + hi) >> 1;
    if (batch[mid] < gidx + 1) lo = mid + 1; else hi = mid;
  }
  int end = lo;
  float s = 0.f;
  for (int n = start + grp; n < end; n += 8) s += h[(size_t)n * FEAT + f];
  sums[grp][f] = s;
  __syncthreads();
  if (grp == 0) {
    float tot = 0.f;
#pragma unroll
    for (int gg = 0; gg < 8; ++gg) tot += sums[gg][f];
    int c = end - start;
    prow[f] = (c > 0) ? tot / (float)c : 0.f;
  }
  __syncthreads();
  float a = 0.f;
  for (int k = grp * 16; k < grp * 16 + 16; ++k) a = fmaf(prow[k], lw[(size_t)k * FEAT + f], a);
  __syncthreads();
  sums[grp][f] = a;
  __syncthreads();
  if (grp == 0) {
    float tot = lb[f];
#pragma unroll
    for (int gg = 0; gg < 8; ++gg) tot += sums[gg][f];
    out[(size_t)gidx * FEAT + f] = tot;
  }
}

extern "C" void kernel_launch(void* const* d_in, const int* in_sizes, int n_in,
                              void* d_out, int out_size, void* d_ws, size_t ws_size,
                              hipStream_t stream) {
  const float* x = (const float*)d_in[0];
  const int* ei = (const int*)d_in[1];
  const float* eattr = (const float*)d_in[2];
  const int* batch = (const int*)d_in[3];
  const float* Wl[3] = {(const float*)d_in[4], (const float*)d_in[7], (const float*)d_in[10]};
  const float* rl[3] = {(const float*)d_in[5], (const float*)d_in[8], (const float*)d_in[11]};
  const float* bl[3] = {(const float*)d_in[6], (const float*)d_in[9], (const float*)d_in[12]};
  const float* lw = (const float*)d_in[13];
  const float* lb = (const float*)d_in[14];
  float* out = (float*)d_out;
  (void)n_in; (void)in_sizes; (void)out_size;

  // ---- workspace carve ----
  size_t pos = 0;
  char* base = (char*)d_ws;
  auto alloc = [&](size_t bytes) { char* q = base + pos; pos += align256(bytes); return q; };
  int* seg = (int*)alloc(sizeof(int) * (size_t)N_EDGESC);
  int* cntcur = (int*)alloc(sizeof(int) * (size_t)2 * NSEG);
  int* cnt = cntcur;
  int* cursor = cntcur + NSEG;
  int* offsets = (int*)alloc(sizeof(int) * (size_t)(NSEG + 1));
  int* bsums = (int*)alloc(sizeof(int) * 1024);
  int* ssrc = (int*)alloc(sizeof(int) * (size_t)N_EDGESC);
  float* h1 = (float*)alloc(sizeof(float) * (size_t)N_NODESC * FEAT);
  float* h2 = (float*)alloc(sizeof(float) * (size_t)N_NODESC * FEAT);
  unsigned short* whi = (unsigned short*)alloc(sizeof(unsigned short) * (size_t)WPACK_ELEMS);
  unsigned short* wlo = (unsigned short*)alloc(sizeof(unsigned short) * (size_t)WPACK_ELEMS);
  size_t remain = (ws_size > pos) ? (ws_size - pos) : 0;
  long long cn = (long long)(remain / (sizeof(float) * NREL * FEAT));
  int chunkNodes = (cn > N_NODESC) ? N_NODESC : (int)cn;
  chunkNodes &= ~127;
  if (chunkNodes < 128) chunkNodes = 128;
  float* aggbuf = (float*)(base + pos);
  int nchunks = (N_NODESC + chunkNodes - 1) / chunkNodes;

  // ---- build CSR ----
  hipLaunchKernelGGL(k_zero, dim3(2048), dim3(256), 0, stream, cntcur, 2 * NSEG);
  hipLaunchKernelGGL(k_edge_hist, dim3((N_EDGESC + 255) / 256), dim3(256), 0, stream,
                     ei, eattr, seg, cnt);
  int nbScan = (NSEG + 4095) / 4096;  // 98
  hipLaunchKernelGGL(k_scan1, dim3(nbScan), dim3(256), 0, stream, cnt, offsets + 1, bsums, NSEG);
  hipLaunchKernelGGL(k_scan2, dim3(1), dim3(128), 0, stream, bsums, nbScan);
  hipLaunchKernelGGL(k_scan3, dim3((NSEG + 255) / 256), dim3(256), 0, stream, offsets, bsums, NSEG);
  hipLaunchKernelGGL(k_scatter, dim3((N_EDGESC + 255) / 256), dim3(256), 0, stream,
                     ei, seg, offsets, cursor, ssrc);

  // ---- 3 RGCN layers ----
  const float* inPtr = x;
  float* outPtr = h1;
  for (int L = 0; L < 3; ++L) {
    hipLaunchKernelGGL(k_wpack, dim3((WPACK_ELEMS + 255) / 256), dim3(256), 0, stream,
                       Wl[L], rl[L], whi, wlo);
    for (int c = 0; c < nchunks; ++c) {
      int nodeBase = c * chunkNodes;
      int rowsC = N_NODESC - nodeBase;
      if (rowsC > chunkNodes) rowsC = chunkNodes;
      int segCount = rowsC * NREL;
      int aggBlocks = (segCount * 32 + 255) / 256;
      hipLaunchKernelGGL(k_agg, dim3(aggBlocks), dim3(256), 0, stream,
                         inPtr, offsets, ssrc, aggbuf, nodeBase * NREL, segCount);
      hipLaunchKernelGGL(k_gemm_mfma, dim3((rowsC + 127) / 128), dim3(256), 0, stream,
                         aggbuf, inPtr, whi, wlo, bl[L], outPtr, nodeBase, rowsC);
    }
    inPtr = outPtr;
    outPtr = (L == 0) ? h2 : h1;
  }

  // ---- pool + final linear ----
  hipLaunchKernelGGL(k_pool, dim3(NGRAPH), dim3(1024), 0, stream, h1, batch, lw, lb, out);
}

// Round 8
// 852.863 us; speedup vs baseline: 1.3047x; 1.1388x over previous
//
#include <hip/hip_runtime.h>
#include <hip/hip_fp16.h>

#define N_NODESC 50000
#define N_EDGESC 1600000
#define FEAT 128
#define NREL 8
#define NSEG (N_NODESC * NREL)
#define NGRAPH 64
#define KTOT 1152          // 8*128 agg + 128 root
#define NKC 36             // KTOT/32
#define WPACK_ELEMS (NKC * 4 * 128 * 8)  // 147456
#define NHALF (N_NODESC * FEAT)

typedef float f32x4 __attribute__((ext_vector_type(4)));
typedef short bf16x8 __attribute__((ext_vector_type(8)));

static inline size_t align256(size_t x) { return (x + 255) & ~(size_t)255; }

__device__ __forceinline__ unsigned short f2bf(float f) {
  unsigned int u = __float_as_uint(f);
  unsigned int r = (u + 0x7fffu + ((u >> 16) & 1u)) >> 16;  // RNE
  return (unsigned short)r;
}
__device__ __forceinline__ float bf2f(unsigned short h) {
  return __uint_as_float(((unsigned int)h) << 16);
}
__device__ __forceinline__ float4 h4tof4(uint2 r) {
  const __half* h = (const __half*)&r;
  return make_float4(__half2float(h[0]), __half2float(h[1]),
                     __half2float(h[2]), __half2float(h[3]));
}

// ---------------- utility: zero ints ----------------
__global__ void k_zero(int* __restrict__ p, int n) {
  int i = blockIdx.x * blockDim.x + threadIdx.x;
  int stride = gridDim.x * blockDim.x;
  for (; i < n; i += stride) p[i] = 0;
}

// ---------------- fp32 -> fp16 plane ----------------
__global__ void k_cvt16(const float* __restrict__ in, __half* __restrict__ o) {
  int i = blockIdx.x * blockDim.x + threadIdx.x;
  if (i * 4 >= NHALF) return;
  float4 v = *(const float4*)&in[i * 4];
  __half h[4] = {__float2half(v.x), __float2half(v.y), __float2half(v.z), __float2half(v.w)};
  *(uint2*)&o[(size_t)i * 4] = *(uint2*)h;
}

// ---------------- edge type + segment + histogram ----------------
__global__ void k_edge_hist(const int* __restrict__ ei, const float* __restrict__ eattr,
                            int* __restrict__ seg, int* __restrict__ cnt) {
  int e = blockIdx.x * blockDim.x + threadIdx.x;
  if (e >= N_EDGESC) return;
  int dst = ei[N_EDGESC + e];
  const float4* ap = (const float4*)(eattr + (size_t)e * 8);
  float4 a0 = ap[0], a1 = ap[1];
  int ty = 0;
  if (a0.y > 0.5f) ty = 1;
  if (a0.z > 0.5f) ty = 2;
  if (a0.w > 0.5f) ty = 3;
  if (a1.x > 0.5f) ty = 4;
  if (a1.y > 0.5f) ty = 5;
  if (a1.z > 0.5f) ty = 6;
  if (a1.w > 0.5f) ty = 7;
  int s = dst * NREL + ty;
  seg[e] = s;
  atomicAdd(&cnt[s], 1);
}

// ---------------- scan over NSEG counts ----------------
__global__ void k_scan1(const int* __restrict__ cnt, int* __restrict__ outIncl,
                        int* __restrict__ bsums, int n) {
  __shared__ int sd[256];
  int t = threadIdx.x;
  int base = blockIdx.x * 4096 + t * 16;
  int v[16];
  int s = 0;
#pragma unroll
  for (int j = 0; j < 16; ++j) {
    int idx = base + j;
    int x = (idx < n) ? cnt[idx] : 0;
    s += x;
    v[j] = s;
  }
  sd[t] = s;
  __syncthreads();
  for (int off = 1; off < 256; off <<= 1) {
    int add = (t >= off) ? sd[t - off] : 0;
    __syncthreads();
    sd[t] += add;
    __syncthreads();
  }
  int prev = (t > 0) ? sd[t - 1] : 0;
#pragma unroll
  for (int j = 0; j < 16; ++j) {
    int idx = base + j;
    if (idx < n) outIncl[idx] = prev + v[j];
  }
  if (t == 255) bsums[blockIdx.x] = sd[255];
}

__global__ void k_scan2(int* __restrict__ bsums, int nb) {
  __shared__ int sd[128];
  int t = threadIdx.x;
  int v = (t < nb) ? bsums[t] : 0;
  sd[t] = v;
  __syncthreads();
  for (int off = 1; off < 128; off <<= 1) {
    int add = (t >= off) ? sd[t - off] : 0;
    __syncthreads();
    sd[t] += add;
    __syncthreads();
  }
  if (t < nb) bsums[t] = sd[t] - v;  // exclusive
}

__global__ void k_scan3(int* __restrict__ offsets, const int* __restrict__ bsums, int n) {
  int i = blockIdx.x * blockDim.x + threadIdx.x;
  if (i == 0) offsets[0] = 0;
  if (i < n) offsets[i + 1] += bsums[i >> 12];
}

// ---------------- scatter into CSR ----------------
__global__ void k_scatter(const int* __restrict__ ei, const int* __restrict__ seg,
                          const int* __restrict__ offsets, int* __restrict__ cursor,
                          int* __restrict__ ssrc) {
  int e = blockIdx.x * blockDim.x + threadIdx.x;
  if (e >= N_EDGESC) return;
  int s = seg[e];
  int p = offsets[s] + atomicAdd(&cursor[s], 1);
  ssrc[p] = ei[e];
}

// ---------------- segment-parallel mean aggregation (fp16 in, fp16 out) ----------------
// one 32-lane group per segment; lane l handles features [4l, 4l+4)
__global__ __launch_bounds__(256, 8) void k_agg(
    const __half* __restrict__ in, const int* __restrict__ offsets,
    const int* __restrict__ ssrc, __half* __restrict__ agg,
    int segBase, int segCount) {
  int t = blockIdx.x * blockDim.x + threadIdx.x;
  int ul = t >> 5;
  int l = t & 31;
  if (ul >= segCount) return;
  int u = segBase + ul;
  int beg = offsets[u], end = offsets[u + 1];
  float4 s = make_float4(0.f, 0.f, 0.f, 0.f);
  // 4-wide predicated unroll: independent ssrc loads + independent 8B gathers
  for (int base = beg; base < end; base += 4) {
    int last = end - 1;
    int e1 = base + 1 <= last ? base + 1 : last;
    int e2 = base + 2 <= last ? base + 2 : last;
    int e3 = base + 3 <= last ? base + 3 : last;
    int i0 = ssrc[base], i1 = ssrc[e1], i2 = ssrc[e2], i3 = ssrc[e3];
    uint2 r0 = *(const uint2*)&in[(size_t)i0 * FEAT + l * 4];
    uint2 r1 = *(const uint2*)&in[(size_t)i1 * FEAT + l * 4];
    uint2 r2 = *(const uint2*)&in[(size_t)i2 * FEAT + l * 4];
    uint2 r3 = *(const uint2*)&in[(size_t)i3 * FEAT + l * 4];
    float4 v0 = h4tof4(r0), v1 = h4tof4(r1), v2 = h4tof4(r2), v3 = h4tof4(r3);
    s.x += v0.x; s.y += v0.y; s.z += v0.z; s.w += v0.w;
    if (base + 1 < end) { s.x += v1.x; s.y += v1.y; s.z += v1.z; s.w += v1.w; }
    if (base + 2 < end) { s.x += v2.x; s.y += v2.y; s.z += v2.z; s.w += v2.w; }
    if (base + 3 < end) { s.x += v3.x; s.y += v3.y; s.z += v3.z; s.w += v3.w; }
  }
  int c = end - beg;
  if (c > 1) {
    float inv = 1.0f / (float)c;
    s.x *= inv; s.y *= inv; s.z *= inv; s.w *= inv;
  }
  __half hv[4] = {__float2half(s.x), __float2half(s.y), __float2half(s.z), __float2half(s.w)};
  *(uint2*)&agg[(size_t)ul * FEAT + l * 4] = *(uint2*)hv;
}

// ---------------- weight pack: W[8][128][128] + root[128][128] -> bf16 hi/lo ----------------
// fragment-major layout: idx = ((slot*128)+n)*8 + j, slot = kc*4+g, k = kc*32+g*8+j
__global__ void k_wpack(const float* __restrict__ W, const float* __restrict__ root,
                        unsigned short* __restrict__ whi, unsigned short* __restrict__ wlo) {
  int idx = blockIdx.x * 256 + threadIdx.x;
  if (idx >= WPACK_ELEMS) return;
  int j = idx & 7;
  int n = (idx >> 3) & 127;
  int slot = idx >> 10;
  int k = slot * 8 + j;
  float v = (k < 1024) ? W[(size_t)k * 128 + n] : root[(size_t)(k - 1024) * 128 + n];
  unsigned short hi = f2bf(v);
  float lof = v - bf2f(hi);
  whi[idx] = hi;
  wlo[idx] = f2bf(lof);
}

// ---------------- MFMA GEMM: out16 = relu(A @ Wfull + bias), A = [agg16 | in16], K=1152 ----------------
// block: 128 rows x 128 cols, 256 threads (4 waves), wave = 32 rows x 128 cols
__global__ __launch_bounds__(256, 2) void k_gemm_mfma(
    const __half* __restrict__ aggc,  // [rows][1024] chunk-local, fp16
    const __half* __restrict__ xin,   // [N][128] fp16 plane (layer input)
    const unsigned short* __restrict__ Whi, const unsigned short* __restrict__ Wlo,
    const float* __restrict__ bias, __half* __restrict__ out16,
    int n0g, int rows) {
  __shared__ unsigned short Ahi[4 * 128 * 8] __attribute__((aligned(16)));  // [g][row][j]
  __shared__ unsigned short Alo[4 * 128 * 8] __attribute__((aligned(16)));
  __shared__ unsigned short Bhi[4 * 128 * 8] __attribute__((aligned(16)));  // [g][n][j]
  __shared__ unsigned short Blo[4 * 128 * 8] __attribute__((aligned(16)));

  const int t = threadIdx.x;
  const int lane = t & 63, wave = t >> 6;
  const int l15 = lane & 15, lg = lane >> 4;
  const int wrow0 = wave * 32;
  const int m0 = blockIdx.x * 128;
  const int srow = t >> 1, half = t & 1;

  f32x4 acc[2][8];
#pragma unroll
  for (int a = 0; a < 2; ++a)
#pragma unroll
    for (int b = 0; b < 8; ++b) acc[a][b] = (f32x4){0.f, 0.f, 0.f, 0.f};

  for (int kc = 0; kc < NKC; ++kc) {
    // ---- load A slab (fp16, 32B per thread) ----
    int rowc = srow;
    if (m0 + rowc >= rows) rowc = rows - 1 - m0;  // clamp (garbage rows masked later)
    if (rowc < 0) rowc = 0;
    const __half* asrc = (kc < 32)
        ? (aggc + (size_t)(m0 + rowc) * 1024 + kc * 32 + half * 16)
        : (xin + (size_t)(n0g + m0 + rowc) * FEAT + (kc - 32) * 32 + half * 16);
    uint4 av0 = ((const uint4*)asrc)[0];
    uint4 av1 = ((const uint4*)asrc)[1];
    // ---- load B slab (packed bf16 hi/lo, contiguous 8KB each) ----
    const uint4* bhs = (const uint4*)(Whi + (size_t)kc * 4096);
    const uint4* bls = (const uint4*)(Wlo + (size_t)kc * 4096);
    uint4 bh0 = bhs[t * 2], bh1 = bhs[t * 2 + 1];
    uint4 bl0 = bls[t * 2], bl1 = bls[t * 2 + 1];

    __syncthreads();  // previous iteration's LDS reads complete

    // ---- convert fp16 -> bf16 hi/lo and pack A into LDS ----
    __half avbuf[16];
    *(uint4*)&avbuf[0] = av0;
    *(uint4*)&avbuf[8] = av1;
#pragma unroll
    for (int gg = 0; gg < 2; ++gg) {
      union { unsigned short u[8]; uint4 v; } ph, pl;
#pragma unroll
      for (int j = 0; j < 8; ++j) {
        float f = __half2float(avbuf[gg * 8 + j]);
        unsigned short hi = f2bf(f);
        ph.u[j] = hi;
        pl.u[j] = f2bf(f - bf2f(hi));
      }
      int g = half * 2 + gg;
      *(uint4*)&Ahi[((size_t)(g * 128 + srow)) * 8] = ph.v;
      *(uint4*)&Alo[((size_t)(g * 128 + srow)) * 8] = pl.v;
    }
    // ---- store B into LDS (straight copy) ----
    ((uint4*)Bhi)[t * 2] = bh0;
    ((uint4*)Bhi)[t * 2 + 1] = bh1;
    ((uint4*)Blo)[t * 2] = bl0;
    ((uint4*)Blo)[t * 2 + 1] = bl1;

    __syncthreads();

    // ---- fragments + MFMA ----
    bf16x8 ah[2], al[2];
#pragma unroll
    for (int mf = 0; mf < 2; ++mf) {
      int ar = wrow0 + mf * 16 + l15;
      ah[mf] = *(const bf16x8*)&Ahi[((size_t)(lg * 128 + ar)) * 8];
      al[mf] = *(const bf16x8*)&Alo[((size_t)(lg * 128 + ar)) * 8];
    }
#pragma unroll
    for (int nf = 0; nf < 8; ++nf) {
      int bn = nf * 16 + l15;
      bf16x8 bh = *(const bf16x8*)&Bhi[((size_t)(lg * 128 + bn)) * 8];
      bf16x8 bl = *(const bf16x8*)&Blo[((size_t)(lg * 128 + bn)) * 8];
#pragma unroll
      for (int mf = 0; mf < 2; ++mf) {
        acc[mf][nf] = __builtin_amdgcn_mfma_f32_16x16x32_bf16(ah[mf], bh, acc[mf][nf], 0, 0, 0);
        acc[mf][nf] = __builtin_amdgcn_mfma_f32_16x16x32_bf16(ah[mf], bl, acc[mf][nf], 0, 0, 0);
        acc[mf][nf] = __builtin_amdgcn_mfma_f32_16x16x32_bf16(al[mf], bh, acc[mf][nf], 0, 0, 0);
      }
    }
  }

  // ---- epilogue: bias + relu + fp16 store ----
  float bcol[8];
#pragma unroll
  for (int nf = 0; nf < 8; ++nf) bcol[nf] = bias[nf * 16 + l15];
#pragma unroll
  for (int mf = 0; mf < 2; ++mf)
#pragma unroll
    for (int nf = 0; nf < 8; ++nf)
#pragma unroll
      for (int j = 0; j < 4; ++j) {
        int grow = m0 + wrow0 + mf * 16 + lg * 4 + j;
        if (grow < rows) {
          float v = acc[mf][nf][j] + bcol[nf];
          v = v > 0.f ? v : 0.f;
          out16[(size_t)(n0g + grow) * FEAT + nf * 16 + l15] = __float2half(v);
        }
      }
}

// ---------------- global mean pool (fp16 h) + final linear ----------------
__global__ void k_pool(const __half* __restrict__ h, const int* __restrict__ batch,
                       const float* __restrict__ lw, const float* __restrict__ lb,
                       float* __restrict__ out) {
  __shared__ float sums[8][128];
  __shared__ float prow[128];
  int gidx = blockIdx.x, t = threadIdx.x;
  int f = t & 127, grp = t >> 7;
  int lo = 0, hi = N_NODESC;
  while (lo < hi) {
    int mid = (lo + hi) >> 1;
    if (batch[mid] < gidx) lo = mid + 1; else hi = mid;
  }
  int start = lo;
  hi = N_NODESC;
  while (lo < hi) {
    int mid = (lo + hi) >> 1;
    if (batch[mid] < gidx + 1) lo = mid + 1; else hi = mid;
  }
  int end = lo;
  float s = 0.f;
  for (int n = start + grp; n < end; n += 8) s += __half2float(h[(size_t)n * FEAT + f]);
  sums[grp][f] = s;
  __syncthreads();
  if (grp == 0) {
    float tot = 0.f;
#pragma unroll
    for (int gg = 0; gg < 8; ++gg) tot += sums[gg][f];
    int c = end - start;
    prow[f] = (c > 0) ? tot / (float)c : 0.f;
  }
  __syncthreads();
  float a = 0.f;
  for (int k = grp * 16; k < grp * 16 + 16; ++k) a = fmaf(prow[k], lw[(size_t)k * FEAT + f], a);
  __syncthreads();
  sums[grp][f] = a;
  __syncthreads();
  if (grp == 0) {
    float tot = lb[f];
#pragma unroll
    for (int gg = 0; gg < 8; ++gg) tot += sums[gg][f];
    out[(size_t)gidx * FEAT + f] = tot;
  }
}

extern "C" void kernel_launch(void* const* d_in, const int* in_sizes, int n_in,
                              void* d_out, int out_size, void* d_ws, size_t ws_size,
                              hipStream_t stream) {
  const float* x = (const float*)d_in[0];
  const int* ei = (const int*)d_in[1];
  const float* eattr = (const float*)d_in[2];
  const int* batch = (const int*)d_in[3];
  const float* Wl[3] = {(const float*)d_in[4], (const float*)d_in[7], (const float*)d_in[10]};
  const float* rl[3] = {(const float*)d_in[5], (const float*)d_in[8], (const float*)d_in[11]};
  const float* bl[3] = {(const float*)d_in[6], (const float*)d_in[9], (const float*)d_in[12]};
  const float* lw = (const float*)d_in[13];
  const float* lb = (const float*)d_in[14];
  float* out = (float*)d_out;
  (void)n_in; (void)in_sizes; (void)out_size;

  // ---- workspace carve ----
  size_t pos = 0;
  char* base = (char*)d_ws;
  auto alloc = [&](size_t bytes) { char* q = base + pos; pos += align256(bytes); return q; };
  int* seg = (int*)alloc(sizeof(int) * (size_t)N_EDGESC);
  int* cntcur = (int*)alloc(sizeof(int) * (size_t)2 * NSEG);
  int* cnt = cntcur;
  int* cursor = cntcur + NSEG;
  int* offsets = (int*)alloc(sizeof(int) * (size_t)(NSEG + 1));
  int* bsums = (int*)alloc(sizeof(int) * 1024);
  int* ssrc = (int*)alloc(sizeof(int) * (size_t)N_EDGESC);
  __half* p0 = (__half*)alloc(sizeof(__half) * (size_t)NHALF);
  __half* p1 = (__half*)alloc(sizeof(__half) * (size_t)NHALF);
  unsigned short* whi = (unsigned short*)alloc(sizeof(unsigned short) * (size_t)WPACK_ELEMS);
  unsigned short* wlo = (unsigned short*)alloc(sizeof(unsigned short) * (size_t)WPACK_ELEMS);
  size_t remain = (ws_size > pos) ? (ws_size - pos) : 0;
  long long cn = (long long)(remain / (sizeof(__half) * NREL * FEAT));
  int chunkNodes = (cn > N_NODESC) ? N_NODESC : (int)cn;
  chunkNodes &= ~127;
  if (chunkNodes < 128) chunkNodes = 128;
  __half* aggbuf = (__half*)(base + pos);
  int nchunks = (N_NODESC + chunkNodes - 1) / chunkNodes;

  // ---- build CSR ----
  hipLaunchKernelGGL(k_zero, dim3(2048), dim3(256), 0, stream, cntcur, 2 * NSEG);
  hipLaunchKernelGGL(k_edge_hist, dim3((N_EDGESC + 255) / 256), dim3(256), 0, stream,
                     ei, eattr, seg, cnt);
  int nbScan = (NSEG + 4095) / 4096;  // 98
  hipLaunchKernelGGL(k_scan1, dim3(nbScan), dim3(256), 0, stream, cnt, offsets + 1, bsums, NSEG);
  hipLaunchKernelGGL(k_scan2, dim3(1), dim3(128), 0, stream, bsums, nbScan);
  hipLaunchKernelGGL(k_scan3, dim3((NSEG + 255) / 256), dim3(256), 0, stream, offsets, bsums, NSEG);
  hipLaunchKernelGGL(k_scatter, dim3((N_EDGESC + 255) / 256), dim3(256), 0, stream,
                     ei, seg, offsets, cursor, ssrc);

  // ---- x -> fp16 plane ----
  hipLaunchKernelGGL(k_cvt16, dim3((NHALF / 4 + 255) / 256), dim3(256), 0, stream, x, p0);

  // ---- 3 RGCN layers (fp16 activation planes: p0 -> p1 -> p0 -> p1) ----
  const __half* inPtr = p0;
  __half* outPtr = p1;
  for (int L = 0; L < 3; ++L) {
    hipLaunchKernelGGL(k_wpack, dim3((WPACK_ELEMS + 255) / 256), dim3(256), 0, stream,
                       Wl[L], rl[L], whi, wlo);
    for (int c = 0; c < nchunks; ++c) {
      int nodeBase = c * chunkNodes;
      int rowsC = N_NODESC - nodeBase;
      if (rowsC > chunkNodes) rowsC = chunkNodes;
      int segCount = rowsC * NREL;
      int aggBlocks = (segCount * 32 + 255) / 256;
      hipLaunchKernelGGL(k_agg, dim3(aggBlocks), dim3(256), 0, stream,
                         inPtr, offsets, ssrc, aggbuf, nodeBase * NREL, segCount);
      hipLaunchKernelGGL(k_gemm_mfma, dim3((rowsC + 127) / 128), dim3(256), 0, stream,
                         aggbuf, inPtr, whi, wlo, bl[L], outPtr, nodeBase, rowsC);
    }
    const __half* tmp = inPtr;
    inPtr = outPtr;
    outPtr = (__half*)tmp;
  }

  // ---- pool + final linear (last output is p1) ----
  hipLaunchKernelGGL(k_pool, dim3(NGRAPH), dim3(1024), 0, stream, p1, batch, lw, lb, out);
}

// Round 9
// 790.020 us; speedup vs baseline: 1.4085x; 1.0795x over previous
//
#include <hip/hip_runtime.h>
#include <hip/hip_fp16.h>

#define N_NODESC 50000
#define N_EDGESC 1600000
#define FEAT 128
#define NREL 8
#define NSEG (N_NODESC * NREL)
#define NGRAPH 64
#define KTOT 1152          // 8*128 agg + 128 root
#define NKC 36             // KTOT/32
#define WPACK_ELEMS (NKC * 4 * 128 * 8)  // 147456
#define NHALF (N_NODESC * FEAT)

typedef float f32x4 __attribute__((ext_vector_type(4)));
typedef _Float16 f16x8 __attribute__((ext_vector_type(8)));

static inline size_t align256(size_t x) { return (x + 255) & ~(size_t)255; }

__device__ __forceinline__ float4 h4tof4(uint2 r) {
  const __half* h = (const __half*)&r;
  return make_float4(__half2float(h[0]), __half2float(h[1]),
                     __half2float(h[2]), __half2float(h[3]));
}

// ---------------- utility: zero ints ----------------
__global__ void k_zero(int* __restrict__ p, int n) {
  int i = blockIdx.x * blockDim.x + threadIdx.x;
  int stride = gridDim.x * blockDim.x;
  for (; i < n; i += stride) p[i] = 0;
}

// ---------------- fp32 -> fp16 plane ----------------
__global__ void k_cvt16(const float* __restrict__ in, __half* __restrict__ o) {
  int i = blockIdx.x * blockDim.x + threadIdx.x;
  if (i * 4 >= NHALF) return;
  float4 v = *(const float4*)&in[i * 4];
  __half h[4] = {__float2half(v.x), __float2half(v.y), __float2half(v.z), __float2half(v.w)};
  *(uint2*)&o[(size_t)i * 4] = *(uint2*)h;
}

// ---------------- edge type + segment + histogram ----------------
__global__ void k_edge_hist(const int* __restrict__ ei, const float* __restrict__ eattr,
                            int* __restrict__ seg, int* __restrict__ cnt) {
  int e = blockIdx.x * blockDim.x + threadIdx.x;
  if (e >= N_EDGESC) return;
  int dst = ei[N_EDGESC + e];
  const float4* ap = (const float4*)(eattr + (size_t)e * 8);
  float4 a0 = ap[0], a1 = ap[1];
  int ty = 0;
  if (a0.y > 0.5f) ty = 1;
  if (a0.z > 0.5f) ty = 2;
  if (a0.w > 0.5f) ty = 3;
  if (a1.x > 0.5f) ty = 4;
  if (a1.y > 0.5f) ty = 5;
  if (a1.z > 0.5f) ty = 6;
  if (a1.w > 0.5f) ty = 7;
  int s = dst * NREL + ty;
  seg[e] = s;
  atomicAdd(&cnt[s], 1);
}

// ---------------- scan over NSEG counts ----------------
__global__ void k_scan1(const int* __restrict__ cnt, int* __restrict__ outIncl,
                        int* __restrict__ bsums, int n) {
  __shared__ int sd[256];
  int t = threadIdx.x;
  int base = blockIdx.x * 4096 + t * 16;
  int v[16];
  int s = 0;
#pragma unroll
  for (int j = 0; j < 16; ++j) {
    int idx = base + j;
    int x = (idx < n) ? cnt[idx] : 0;
    s += x;
    v[j] = s;
  }
  sd[t] = s;
  __syncthreads();
  for (int off = 1; off < 256; off <<= 1) {
    int add = (t >= off) ? sd[t - off] : 0;
    __syncthreads();
    sd[t] += add;
    __syncthreads();
  }
  int prev = (t > 0) ? sd[t - 1] : 0;
#pragma unroll
  for (int j = 0; j < 16; ++j) {
    int idx = base + j;
    if (idx < n) outIncl[idx] = prev + v[j];
  }
  if (t == 255) bsums[blockIdx.x] = sd[255];
}

__global__ void k_scan2(int* __restrict__ bsums, int nb) {
  __shared__ int sd[128];
  int t = threadIdx.x;
  int v = (t < nb) ? bsums[t] : 0;
  sd[t] = v;
  __syncthreads();
  for (int off = 1; off < 128; off <<= 1) {
    int add = (t >= off) ? sd[t - off] : 0;
    __syncthreads();
    sd[t] += add;
    __syncthreads();
  }
  if (t < nb) bsums[t] = sd[t] - v;  // exclusive
}

__global__ void k_scan3(int* __restrict__ offsets, const int* __restrict__ bsums, int n) {
  int i = blockIdx.x * blockDim.x + threadIdx.x;
  if (i == 0) offsets[0] = 0;
  if (i < n) offsets[i + 1] += bsums[i >> 12];
}

// ---------------- scatter into CSR ----------------
__global__ void k_scatter(const int* __restrict__ ei, const int* __restrict__ seg,
                          const int* __restrict__ offsets, int* __restrict__ cursor,
                          int* __restrict__ ssrc) {
  int e = blockIdx.x * blockDim.x + threadIdx.x;
  if (e >= N_EDGESC) return;
  int s = seg[e];
  int p = offsets[s] + atomicAdd(&cursor[s], 1);
  ssrc[p] = ei[e];
}

// ---------------- node-level mean aggregation (fp16 in/out) ----------------
// one 32-lane group per NODE; inner loop over the 8 relations; lane l = feats [4l,4l+4)
__global__ __launch_bounds__(256, 8) void k_agg(
    const __half* __restrict__ in, const int* __restrict__ offsets,
    const int* __restrict__ ssrc, __half* __restrict__ agg,
    int nodeBase, int nodeCount) {
  int t = blockIdx.x * blockDim.x + threadIdx.x;
  int un = t >> 5;
  int l = t & 31;
  if (un >= nodeCount) return;
  int node = nodeBase + un;
  for (int r = 0; r < NREL; ++r) {
    int sidx = node * NREL + r;
    int beg = offsets[sidx], end = offsets[sidx + 1];
    float4 s = make_float4(0.f, 0.f, 0.f, 0.f);
    for (int base = beg; base < end; base += 4) {
      int last = end - 1;
      int e1 = base + 1 <= last ? base + 1 : last;
      int e2 = base + 2 <= last ? base + 2 : last;
      int e3 = base + 3 <= last ? base + 3 : last;
      int i0 = ssrc[base], i1 = ssrc[e1], i2 = ssrc[e2], i3 = ssrc[e3];
      uint2 r0 = *(const uint2*)&in[(size_t)i0 * FEAT + l * 4];
      uint2 r1 = *(const uint2*)&in[(size_t)i1 * FEAT + l * 4];
      uint2 r2 = *(const uint2*)&in[(size_t)i2 * FEAT + l * 4];
      uint2 r3 = *(const uint2*)&in[(size_t)i3 * FEAT + l * 4];
      float4 v0 = h4tof4(r0), v1 = h4tof4(r1), v2 = h4tof4(r2), v3 = h4tof4(r3);
      s.x += v0.x; s.y += v0.y; s.z += v0.z; s.w += v0.w;
      if (base + 1 < end) { s.x += v1.x; s.y += v1.y; s.z += v1.z; s.w += v1.w; }
      if (base + 2 < end) { s.x += v2.x; s.y += v2.y; s.z += v2.z; s.w += v2.w; }
      if (base + 3 < end) { s.x += v3.x; s.y += v3.y; s.z += v3.z; s.w += v3.w; }
    }
    int c = end - beg;
    if (c > 1) {
      float inv = 1.0f / (float)c;
      s.x *= inv; s.y *= inv; s.z *= inv; s.w *= inv;
    }
    __half hv[4] = {__float2half(s.x), __float2half(s.y), __float2half(s.z), __float2half(s.w)};
    *(uint2*)&agg[((size_t)un * NREL + r) * FEAT + l * 4] = *(uint2*)hv;
  }
}

// ---------------- weight pack: W[8][128][128] + root[128][128] -> fp16 hi/lo ----------------
// fragment-major layout: idx = ((slot*128)+n)*8 + j, slot = kc*4+g, k = kc*32+g*8+j
__global__ void k_wpack(const float* __restrict__ W, const float* __restrict__ root,
                        __half* __restrict__ whi, __half* __restrict__ wlo) {
  int idx = blockIdx.x * 256 + threadIdx.x;
  if (idx >= WPACK_ELEMS) return;
  int j = idx & 7;
  int n = (idx >> 3) & 127;
  int slot = idx >> 10;
  int k = slot * 8 + j;
  float v = (k < 1024) ? W[(size_t)k * 128 + n] : root[(size_t)(k - 1024) * 128 + n];
  __half hi = __float2half(v);
  float lof = v - __half2float(hi);
  whi[idx] = hi;
  wlo[idx] = __float2half(lof);
}

// ---------------- fp16 MFMA GEMM: out16 = relu(A @ (Bhi+Blo) + bias), K=1152 ----------------
// block: 128 rows x 128 cols, 256 threads (4 waves), wave = 32 rows x 128 cols
__global__ __launch_bounds__(256, 4) void k_gemm_mfma(
    const __half* __restrict__ aggc,  // [rows][1024] chunk-local, fp16
    const __half* __restrict__ xin,   // [N][128] fp16 plane (layer input)
    const __half* __restrict__ Whi, const __half* __restrict__ Wlo,
    const float* __restrict__ bias, __half* __restrict__ out16,
    int n0g, int rows) {
  __shared__ __half Ah[4 * 128 * 8] __attribute__((aligned(16)));   // [g][row][j]
  __shared__ __half Bh[4 * 128 * 8] __attribute__((aligned(16)));   // [g][n][j]
  __shared__ __half Bl[4 * 128 * 8] __attribute__((aligned(16)));

  const int t = threadIdx.x;
  const int lane = t & 63, wave = t >> 6;
  const int l15 = lane & 15, lg = lane >> 4;
  const int wrow0 = wave * 32;
  const int m0 = blockIdx.x * 128;
  const int srow = t >> 1, half = t & 1;

  f32x4 acc[2][8];
#pragma unroll
  for (int a = 0; a < 2; ++a)
#pragma unroll
    for (int b = 0; b < 8; ++b) acc[a][b] = (f32x4){0.f, 0.f, 0.f, 0.f};

  for (int kc = 0; kc < NKC; ++kc) {
    // ---- load A slab (fp16, 32B per thread: rows srow, k-halves [half*16,+16)) ----
    int rowc = srow;
    if (m0 + rowc >= rows) rowc = rows - 1 - m0;  // clamp (garbage rows masked later)
    if (rowc < 0) rowc = 0;
    const __half* asrc = (kc < 32)
        ? (aggc + (size_t)(m0 + rowc) * 1024 + kc * 32 + half * 16)
        : (xin + (size_t)(n0g + m0 + rowc) * FEAT + (kc - 32) * 32 + half * 16);
    uint4 av0 = ((const uint4*)asrc)[0];
    uint4 av1 = ((const uint4*)asrc)[1];
    // ---- load B slab (packed fp16 hi/lo, contiguous 8KB each) ----
    const uint4* bhs = (const uint4*)(Whi + (size_t)kc * 4096);
    const uint4* bls = (const uint4*)(Wlo + (size_t)kc * 4096);
    uint4 bh0 = bhs[t * 2], bh1 = bhs[t * 2 + 1];
    uint4 bl0 = bls[t * 2], bl1 = bls[t * 2 + 1];

    __syncthreads();  // previous iteration's LDS reads complete

    // ---- straight copies into LDS (no conversion!) ----
    {
      int g0 = half * 2;
      *(uint4*)&Ah[((size_t)(g0 * 128 + srow)) * 8] = av0;
      *(uint4*)&Ah[((size_t)((g0 + 1) * 128 + srow)) * 8] = av1;
      ((uint4*)Bh)[t * 2] = bh0;
      ((uint4*)Bh)[t * 2 + 1] = bh1;
      ((uint4*)Bl)[t * 2] = bl0;
      ((uint4*)Bl)[t * 2 + 1] = bl1;
    }
    __syncthreads();

    // ---- fragments + MFMA (2 terms: A*Bhi + A*Blo) ----
    f16x8 af[2];
#pragma unroll
    for (int mf = 0; mf < 2; ++mf) {
      int ar = wrow0 + mf * 16 + l15;
      af[mf] = *(const f16x8*)&Ah[((size_t)(lg * 128 + ar)) * 8];
    }
#pragma unroll
    for (int nf = 0; nf < 8; ++nf) {
      int bn = nf * 16 + l15;
      f16x8 bh = *(const f16x8*)&Bh[((size_t)(lg * 128 + bn)) * 8];
      f16x8 bl = *(const f16x8*)&Bl[((size_t)(lg * 128 + bn)) * 8];
#pragma unroll
      for (int mf = 0; mf < 2; ++mf) {
        acc[mf][nf] = __builtin_amdgcn_mfma_f32_16x16x32_f16(af[mf], bh, acc[mf][nf], 0, 0, 0);
        acc[mf][nf] = __builtin_amdgcn_mfma_f32_16x16x32_f16(af[mf], bl, acc[mf][nf], 0, 0, 0);
      }
    }
  }

  // ---- epilogue: bias + relu + fp16 store ----
  float bcol[8];
#pragma unroll
  for (int nf = 0; nf < 8; ++nf) bcol[nf] = bias[nf * 16 + l15];
#pragma unroll
  for (int mf = 0; mf < 2; ++mf)
#pragma unroll
    for (int nf = 0; nf < 8; ++nf)
#pragma unroll
      for (int j = 0; j < 4; ++j) {
        int grow = m0 + wrow0 + mf * 16 + lg * 4 + j;
        if (grow < rows) {
          float v = acc[mf][nf][j] + bcol[nf];
          v = v > 0.f ? v : 0.f;
          out16[(size_t)(n0g + grow) * FEAT + nf * 16 + l15] = __float2half(v);
        }
      }
}

// ---------------- global mean pool (fp16 h) + final linear ----------------
__global__ void k_pool(const __half* __restrict__ h, const int* __restrict__ batch,
                       const float* __restrict__ lw, const float* __restrict__ lb,
                       float* __restrict__ out) {
  __shared__ float sums[8][128];
  __shared__ float prow[128];
  int gidx = blockIdx.x, t = threadIdx.x;
  int f = t & 127, grp = t >> 7;
  int lo = 0, hi = N_NODESC;
  while (lo < hi) {
    int mid = (lo + hi) >> 1;
    if (batch[mid] < gidx) lo = mid + 1; else hi = mid;
  }
  int start = lo;
  hi = N_NODESC;
  while (lo < hi) {
    int mid = (lo + hi) >> 1;
    if (batch[mid] < gidx + 1) lo = mid + 1; else hi = mid;
  }
  int end = lo;
  float s = 0.f;
  for (int n = start + grp; n < end; n += 8) s += __half2float(h[(size_t)n * FEAT + f]);
  sums[grp][f] = s;
  __syncthreads();
  if (grp == 0) {
    float tot = 0.f;
#pragma unroll
    for (int gg = 0; gg < 8; ++gg) tot += sums[gg][f];
    int c = end - start;
    prow[f] = (c > 0) ? tot / (float)c : 0.f;
  }
  __syncthreads();
  float a = 0.f;
  for (int k = grp * 16; k < grp * 16 + 16; ++k) a = fmaf(prow[k], lw[(size_t)k * FEAT + f], a);
  __syncthreads();
  sums[grp][f] = a;
  __syncthreads();
  if (grp == 0) {
    float tot = lb[f];
#pragma unroll
    for (int gg = 0; gg < 8; ++gg) tot += sums[gg][f];
    out[(size_t)gidx * FEAT + f] = tot;
  }
}

extern "C" void kernel_launch(void* const* d_in, const int* in_sizes, int n_in,
                              void* d_out, int out_size, void* d_ws, size_t ws_size,
                              hipStream_t stream) {
  const float* x = (const float*)d_in[0];
  const int* ei = (const int*)d_in[1];
  const float* eattr = (const float*)d_in[2];
  const int* batch = (const int*)d_in[3];
  const float* Wl[3] = {(const float*)d_in[4], (const float*)d_in[7], (const float*)d_in[10]};
  const float* rl[3] = {(const float*)d_in[5], (const float*)d_in[8], (const float*)d_in[11]};
  const float* bl[3] = {(const float*)d_in[6], (const float*)d_in[9], (const float*)d_in[12]};
  const float* lw = (const float*)d_in[13];
  const float* lb = (const float*)d_in[14];
  float* out = (float*)d_out;
  (void)n_in; (void)in_sizes; (void)out_size;

  // ---- workspace carve ----
  size_t pos = 0;
  char* base = (char*)d_ws;
  auto alloc = [&](size_t bytes) { char* q = base + pos; pos += align256(bytes); return q; };
  int* seg = (int*)alloc(sizeof(int) * (size_t)N_EDGESC);
  int* cntcur = (int*)alloc(sizeof(int) * (size_t)2 * NSEG);
  int* cnt = cntcur;
  int* cursor = cntcur + NSEG;
  int* offsets = (int*)alloc(sizeof(int) * (size_t)(NSEG + 1));
  int* bsums = (int*)alloc(sizeof(int) * 1024);
  int* ssrc = (int*)alloc(sizeof(int) * (size_t)N_EDGESC);
  __half* p0 = (__half*)alloc(sizeof(__half) * (size_t)NHALF);
  __half* p1 = (__half*)alloc(sizeof(__half) * (size_t)NHALF);
  __half* whi = (__half*)alloc(sizeof(__half) * (size_t)WPACK_ELEMS);
  __half* wlo = (__half*)alloc(sizeof(__half) * (size_t)WPACK_ELEMS);
  size_t remain = (ws_size > pos) ? (ws_size - pos) : 0;
  long long cn = (long long)(remain / (sizeof(__half) * NREL * FEAT));
  int chunkNodes = (cn > N_NODESC) ? N_NODESC : (int)cn;
  chunkNodes &= ~127;
  if (chunkNodes < 128) chunkNodes = 128;
  __half* aggbuf = (__half*)(base + pos);
  int nchunks = (N_NODESC + chunkNodes - 1) / chunkNodes;

  // ---- build CSR ----
  hipLaunchKernelGGL(k_zero, dim3(2048), dim3(256), 0, stream, cntcur, 2 * NSEG);
  hipLaunchKernelGGL(k_edge_hist, dim3((N_EDGESC + 255) / 256), dim3(256), 0, stream,
                     ei, eattr, seg, cnt);
  int nbScan = (NSEG + 4095) / 4096;  // 98
  hipLaunchKernelGGL(k_scan1, dim3(nbScan), dim3(256), 0, stream, cnt, offsets + 1, bsums, NSEG);
  hipLaunchKernelGGL(k_scan2, dim3(1), dim3(128), 0, stream, bsums, nbScan);
  hipLaunchKernelGGL(k_scan3, dim3((NSEG + 255) / 256), dim3(256), 0, stream, offsets, bsums, NSEG);
  hipLaunchKernelGGL(k_scatter, dim3((N_EDGESC + 255) / 256), dim3(256), 0, stream,
                     ei, seg, offsets, cursor, ssrc);

  // ---- x -> fp16 plane ----
  hipLaunchKernelGGL(k_cvt16, dim3((NHALF / 4 + 255) / 256), dim3(256), 0, stream, x, p0);

  // ---- 3 RGCN layers (fp16 activation planes) ----
  const __half* inPtr = p0;
  __half* outPtr = p1;
  for (int L = 0; L < 3; ++L) {
    hipLaunchKernelGGL(k_wpack, dim3((WPACK_ELEMS + 255) / 256), dim3(256), 0, stream,
                       Wl[L], rl[L], whi, wlo);
    for (int c = 0; c < nchunks; ++c) {
      int nodeBase = c * chunkNodes;
      int rowsC = N_NODESC - nodeBase;
      if (rowsC > chunkNodes) rowsC = chunkNodes;
      int aggBlocks = (rowsC * 32 + 255) / 256;
      hipLaunchKernelGGL(k_agg, dim3(aggBlocks), dim3(256), 0, stream,
                         inPtr, offsets, ssrc, aggbuf, nodeBase, rowsC);
      hipLaunchKernelGGL(k_gemm_mfma, dim3((rowsC + 127) / 128), dim3(256), 0, stream,
                         aggbuf, inPtr, whi, wlo, bl[L], outPtr, nodeBase, rowsC);
    }
    const __half* tmp = inPtr;
    inPtr = outPtr;
    outPtr = (__half*)tmp;
  }

  // ---- pool + final linear (last output is p1) ----
  hipLaunchKernelGGL(k_pool, dim3(NGRAPH), dim3(1024), 0, stream, p1, batch, lw, lb, out);
}